// Round 3
// baseline (145.142 us; speedup 1.0000x reference)
//
#include <hip/hip_runtime.h>
#include <math.h>

// Problem constants: B=2, N=1024, H=128, E=32
#define NN 1024
#define NBLK 512
#define NTHR 256

// Math (fused weights, as R1):
//   t[bn,o]  = sum_h nf[bn,h]*Wt[o,h] + bt[o]
//   g[bn,e'] = sum_k nf[bn,k]*At[k,e'] + c[e'],  At[k,e'] = sum_o W1'[e',o]*Wt[o,k]
//     (e'=0..31 -> W1i half, b1 folded into c; e'=32..63 -> W1j half)
//   ew(n,m)  = b2 + sum_e relu(g[n,e] + g[m,32+e]) * W2[e]
//   out      = sigmoid(ew) * adj[n,m]      (exactly 0 where adj==0 -> skip)
//
// ws float layout:
//   [0..3]        two u32 grid-barrier counters (memset to 0 each call)
//   [4..8195]     At[128*64]
//   [8196..8259]  c[64]
//   [8260..]      gall[2048*64]

__device__ __forceinline__ void grid_barrier(unsigned* ctr, int tid) {
    __threadfence();                    // make this thread's global stores visible
    __syncthreads();                    // whole block done + fenced
    if (tid == 0) {
        __hip_atomic_fetch_add(ctr, 1u, __ATOMIC_ACQ_REL, __HIP_MEMORY_SCOPE_AGENT);
        while (__hip_atomic_load(ctr, __ATOMIC_ACQUIRE, __HIP_MEMORY_SCOPE_AGENT) < NBLK)
            __builtin_amdgcn_s_sleep(2);
    }
    __syncthreads();
}

__global__ __launch_bounds__(NTHR, 2) void fused_kernel(
    const float* __restrict__ nf,  const float* __restrict__ adj,
    const float* __restrict__ Wt,  const float* __restrict__ bt,
    const float* __restrict__ W1,  const float* __restrict__ b1,
    const float* __restrict__ W2,  const float* __restrict__ b2,
    float* __restrict__ ws,        float* __restrict__ out)
{
    unsigned* ctr = (unsigned*)ws;
    float* At   = ws + 4;
    float* c    = ws + 8196;
    float* gall = ws + 8260;

    const int bid = blockIdx.x;
    const int tid = threadIdx.x;

    __shared__ float s_w1[2][128];
    __shared__ float s_bt[128];
    __shared__ float s_red[256];
    __shared__ float s_u[4][32];
    __shared__ float s_w2[32];

    // ---------------- Phase A: At = W1'*Wt, c = W1'*bt (+b1) ----------------
    if (bid < 32) {
        const int sub  = tid >> 7;          // 0/1: two e' per block
        const int t128 = tid & 127;
        const int ep   = bid * 2 + sub;
        const int e    = ep & 31;
        const int half = ep >> 5;

        s_w1[sub][t128] = W1[e * 256 + half * 128 + t128];
        if (tid < 128) s_bt[tid] = bt[tid];
        __syncthreads();

        float a0 = 0.f, a1 = 0.f, a2 = 0.f, a3 = 0.f;
        #pragma unroll 8
        for (int o = 0; o < 128; o += 4) {
            a0 = fmaf(s_w1[sub][o + 0], Wt[(o + 0) * 128 + t128], a0);
            a1 = fmaf(s_w1[sub][o + 1], Wt[(o + 1) * 128 + t128], a1);
            a2 = fmaf(s_w1[sub][o + 2], Wt[(o + 2) * 128 + t128], a2);
            a3 = fmaf(s_w1[sub][o + 3], Wt[(o + 3) * 128 + t128], a3);
        }
        At[t128 * 64 + ep] = (a0 + a1) + (a2 + a3);

        s_red[tid] = s_w1[sub][t128] * s_bt[t128];
        __syncthreads();
        for (int s = 64; s > 0; s >>= 1) {
            if (t128 < s) s_red[tid] += s_red[tid + s];
            __syncthreads();
        }
        if (t128 == 0) c[ep] = s_red[sub * 128] + (half == 0 ? b1[e] : 0.f);
    }

    grid_barrier(&ctr[0], tid);

    // ---------------- Phase B: gall = nf*At + c (one wave per node) ---------
    {
        const int bn   = bid * 4 + (tid >> 6);  // wave-uniform, 0..2047
        const int lane = tid & 63;
        const int g    = lane & 15;
        const int krep = lane >> 4;

        const float* nfrow = nf + bn * 128;
        float4 acc = make_float4(0.f, 0.f, 0.f, 0.f);

        #pragma unroll 8
        for (int i = 0; i < 32; ++i) {
            const int k = 4 * i + krep;
            const float nv = nfrow[k];
            const float4 av = *reinterpret_cast<const float4*>(At + k * 64 + 4 * g);
            acc.x = fmaf(nv, av.x, acc.x);
            acc.y = fmaf(nv, av.y, acc.y);
            acc.z = fmaf(nv, av.z, acc.z);
            acc.w = fmaf(nv, av.w, acc.w);
        }
        acc.x += __shfl_xor(acc.x, 16, 64);
        acc.y += __shfl_xor(acc.y, 16, 64);
        acc.z += __shfl_xor(acc.z, 16, 64);
        acc.w += __shfl_xor(acc.w, 16, 64);
        acc.x += __shfl_xor(acc.x, 32, 64);
        acc.y += __shfl_xor(acc.y, 32, 64);
        acc.z += __shfl_xor(acc.z, 32, 64);
        acc.w += __shfl_xor(acc.w, 32, 64);

        if (krep == 0) {
            const float4 cv = *reinterpret_cast<const float4*>(c + 4 * g);
            float4 r;
            r.x = acc.x + cv.x;
            r.y = acc.y + cv.y;
            r.z = acc.z + cv.z;
            r.w = acc.w + cv.w;
            *reinterpret_cast<float4*>(gall + bn * 64 + 4 * g) = r;
        }
    }

    grid_barrier(&ctr[1], tid);

    // ---------------- Phase C: edge rows (4 per block) ----------------------
    if (tid < 128) {
        const int rr = tid >> 5, ee = tid & 31;
        s_u[rr][ee] = gall[(bid * 4 + rr) * 64 + ee];
    }
    if (tid < 32) s_w2[tid] = W2[tid];
    __syncthreads();
    const float b2v = b2[0];

    #pragma unroll
    for (int r = 0; r < 4; ++r) {
        const int flat = bid * 4 + r;         // (b,n) flattened row
        const int nr   = flat & (NN - 1);
        const int br   = flat >> 10;
        const int m0   = tid * 4;

        const float4 a4 = *reinterpret_cast<const float4*>(adj + nr * NN + m0);
        float4 r4;
        const float* ap = &a4.x;
        float* rp = &r4.x;

        #pragma unroll
        for (int cc = 0; cc < 4; ++cc) {
            const float a = ap[cc];
            float v = 0.f;
            if (a != 0.f) {
                const float* gj = gall + (br * NN + m0 + cc) * 64 + 32;
                float ew = b2v;
                #pragma unroll
                for (int j = 0; j < 8; ++j) {
                    const float4 gv = *reinterpret_cast<const float4*>(gj + 4 * j);
                    const float v0 = fmaxf(s_u[r][4 * j + 0] + gv.x, 0.f);
                    const float v1 = fmaxf(s_u[r][4 * j + 1] + gv.y, 0.f);
                    const float v2 = fmaxf(s_u[r][4 * j + 2] + gv.z, 0.f);
                    const float v3 = fmaxf(s_u[r][4 * j + 3] + gv.w, 0.f);
                    ew = fmaf(v0, s_w2[4 * j + 0], ew);
                    ew = fmaf(v1, s_w2[4 * j + 1], ew);
                    ew = fmaf(v2, s_w2[4 * j + 2], ew);
                    ew = fmaf(v3, s_w2[4 * j + 3], ew);
                }
                v = a / (1.f + __expf(-ew));
            }
            rp[cc] = v;
        }
        *reinterpret_cast<float4*>(out + (size_t)flat * NN + m0) = r4;
    }
}

extern "C" void kernel_launch(void* const* d_in, const int* in_sizes, int n_in,
                              void* d_out, int out_size, void* d_ws, size_t ws_size,
                              hipStream_t stream)
{
    const float* nf  = (const float*)d_in[0];
    const float* adj = (const float*)d_in[1];
    const float* Wt  = (const float*)d_in[2];
    const float* bt  = (const float*)d_in[3];
    const float* W1  = (const float*)d_in[4];
    const float* b1  = (const float*)d_in[5];
    const float* W2  = (const float*)d_in[6];
    const float* b2  = (const float*)d_in[7];
    float* out = (float*)d_out;
    float* ws  = (float*)d_ws;

    // zero the two grid-barrier counters (poison-proof, graph-capturable)
    hipMemsetAsync(d_ws, 0, 16, stream);

    hipLaunchKernelGGL(fused_kernel, dim3(NBLK), dim3(NTHR), 0, stream,
                       nf, adj, Wt, bt, W1, b1, W2, b2, ws, out);
}

// Round 4
// 19.261 us; speedup vs baseline: 7.5356x; 7.5356x over previous
//
#include <hip/hip_runtime.h>
#include <math.h>

// Problem constants: B=2, N=1024, H=128, E=32
#define NN 1024
#define PADW 132   // padded LDS row stride (words): 132%32=4 -> uniform banks for
                   // lane-consecutive row access; 132%4==0 -> float4 aligned

// Math:
//   t[bn,o]  = sum_h nf[bn,h]*Wt[o,h] + bt[o]
//   g[bn,e'] : e'=0..31  -> sum_o t[bn,o]*W1[e, o]    + b1[e]   (i-half)
//              e'=32..63 -> sum_o t[bn,o]*W1[e, 128+o]          (j-half)
//   ew(n,m)  = b2 + sum_e relu(g[n,e] + g[m,32+e]) * W2[e]
//   out      = sigmoid(ew) * adj[n,m]   (exactly 0 where adj==0 -> skip)
// ws layout (floats): gall[2048*64]

__device__ __forceinline__ float hsum4(float4 a) {
    return (a.x + a.y) + (a.z + a.w);
}

// k1: 256 blocks x 256 threads, 8 nodes/block. Weights staged in LDS (coalesced
// global loads), then conflict-free register-tiled dots.
__global__ __launch_bounds__(256) void gall_kernel(
    const float* __restrict__ nf, const float* __restrict__ Wt,
    const float* __restrict__ bt, const float* __restrict__ W1,
    const float* __restrict__ b1, float* __restrict__ gall)
{
    __shared__ float s_Wt[128 * PADW];  // Wt[o][h]
    __shared__ float s_W1[64 * PADW];   // W1'[ep][o], ep = half*32+e
    __shared__ float s_nf[8 * 128];
    __shared__ float s_t[8 * PADW];

    const int tid = threadIdx.x;
    const int nb  = blockIdx.x * 8;

    for (int idx = tid; idx < 128 * 128; idx += 256)
        s_Wt[(idx >> 7) * PADW + (idx & 127)] = Wt[idx];
    for (int idx = tid; idx < 32 * 256; idx += 256) {
        const int e = idx >> 8, j = idx & 255;
        const int half = j >> 7, o = j & 127;
        s_W1[(half * 32 + e) * PADW + o] = W1[idx];
    }
    for (int idx = tid; idx < 8 * 128; idx += 256)
        s_nf[idx] = nf[nb * 128 + idx];
    __syncthreads();

    // t-step: t[8][128]. thread: o = tid&127 (lane-consecutive -> uniform banks),
    // node group n0 = (tid>>7)*4. 1 Wt stream-read per 16 FMA.
    {
        const int o  = tid & 127;
        const int n0 = (tid >> 7) * 4;
        const float* wrow = s_Wt + o * PADW;
        float4 A0 = {0,0,0,0}, A1 = {0,0,0,0}, A2 = {0,0,0,0}, A3 = {0,0,0,0};
        #pragma unroll 8
        for (int hc = 0; hc < 32; ++hc) {
            const float4 w  = *reinterpret_cast<const float4*>(wrow + 4 * hc);
            const float4 x0 = *reinterpret_cast<const float4*>(s_nf + (n0 + 0) * 128 + 4 * hc);
            const float4 x1 = *reinterpret_cast<const float4*>(s_nf + (n0 + 1) * 128 + 4 * hc);
            const float4 x2 = *reinterpret_cast<const float4*>(s_nf + (n0 + 2) * 128 + 4 * hc);
            const float4 x3 = *reinterpret_cast<const float4*>(s_nf + (n0 + 3) * 128 + 4 * hc);
            A0.x = fmaf(w.x, x0.x, A0.x); A0.y = fmaf(w.y, x0.y, A0.y);
            A0.z = fmaf(w.z, x0.z, A0.z); A0.w = fmaf(w.w, x0.w, A0.w);
            A1.x = fmaf(w.x, x1.x, A1.x); A1.y = fmaf(w.y, x1.y, A1.y);
            A1.z = fmaf(w.z, x1.z, A1.z); A1.w = fmaf(w.w, x1.w, A1.w);
            A2.x = fmaf(w.x, x2.x, A2.x); A2.y = fmaf(w.y, x2.y, A2.y);
            A2.z = fmaf(w.z, x2.z, A2.z); A2.w = fmaf(w.w, x2.w, A2.w);
            A3.x = fmaf(w.x, x3.x, A3.x); A3.y = fmaf(w.y, x3.y, A3.y);
            A3.z = fmaf(w.z, x3.z, A3.z); A3.w = fmaf(w.w, x3.w, A3.w);
        }
        const float btv = bt[o];
        s_t[(n0 + 0) * PADW + o] = hsum4(A0) + btv;
        s_t[(n0 + 1) * PADW + o] = hsum4(A1) + btv;
        s_t[(n0 + 2) * PADW + o] = hsum4(A2) + btv;
        s_t[(n0 + 3) * PADW + o] = hsum4(A3) + btv;
    }
    __syncthreads();

    // g-step: g[8][64]. thread: ep = tid&63 (uniform banks), nodes n0 = (tid>>6)*2.
    {
        const int ep = tid & 63;
        const int n0 = (tid >> 6) * 2;
        const int e = ep & 31, half = ep >> 5;
        const float* w1row = s_W1 + ep * PADW;
        const float* t0 = s_t + (n0 + 0) * PADW;
        const float* t1 = s_t + (n0 + 1) * PADW;
        float4 A0 = {0,0,0,0}, A1 = {0,0,0,0};
        #pragma unroll 8
        for (int oc = 0; oc < 32; ++oc) {
            const float4 w  = *reinterpret_cast<const float4*>(w1row + 4 * oc);
            const float4 x0 = *reinterpret_cast<const float4*>(t0 + 4 * oc);
            const float4 x1 = *reinterpret_cast<const float4*>(t1 + 4 * oc);
            A0.x = fmaf(w.x, x0.x, A0.x); A0.y = fmaf(w.y, x0.y, A0.y);
            A0.z = fmaf(w.z, x0.z, A0.z); A0.w = fmaf(w.w, x0.w, A0.w);
            A1.x = fmaf(w.x, x1.x, A1.x); A1.y = fmaf(w.y, x1.y, A1.y);
            A1.z = fmaf(w.z, x1.z, A1.z); A1.w = fmaf(w.w, x1.w, A1.w);
        }
        float g0 = hsum4(A0), g1 = hsum4(A1);
        if (half == 0) { const float bv = b1[e]; g0 += bv; g1 += bv; }
        gall[(nb + n0 + 0) * 64 + ep] = g0;   // lanes ep-consecutive -> coalesced
        gall[(nb + n0 + 1) * 64 + ep] = g1;
    }
}

// k2: one block per row n, BOTH batches. LDS worklist compaction: dense lanes
// on the ~5% active edges, then dense float4 stores.
__global__ __launch_bounds__(256) void edge_kernel(
    const float* __restrict__ adj, const float* __restrict__ gall,
    const float* __restrict__ W2, const float* __restrict__ b2,
    float* __restrict__ out)
{
    const int n   = blockIdx.x;
    const int tid = threadIdx.x;

    __shared__ float s_u[2][32];
    __shared__ float s_w2[32];
    __shared__ unsigned s_cnt;
    __shared__ unsigned short s_ent[2048];
    __shared__ float s_res[2048];

    const int m0 = tid * 4;
    const float4 a4 = *reinterpret_cast<const float4*>(adj + n * NN + m0);  // shared by both b

    if (tid < 32)       s_u[0][tid]       = gall[n * 64 + tid];
    else if (tid < 64)  s_u[1][tid & 31]  = gall[(NN + n) * 64 + (tid & 31)];
    else if (tid < 96)  s_w2[tid & 31]    = W2[tid & 31];
    if (tid == 0) s_cnt = 0;
    __syncthreads();

    const float* ap = &a4.x;
    int eidx[8];
    #pragma unroll
    for (int b = 0; b < 2; ++b) {
        #pragma unroll
        for (int cc = 0; cc < 4; ++cc) {
            const int slot = b * 4 + cc;
            eidx[slot] = -1;
            if (ap[cc] != 0.f) {
                const unsigned w = atomicAdd(&s_cnt, 1u);
                s_ent[w] = (unsigned short)((b << 10) | (m0 + cc));
                eidx[slot] = (int)w;
            }
        }
    }
    __syncthreads();
    const unsigned cnt = s_cnt;
    const float b2v = b2[0];

    for (unsigned w = tid; w < cnt; w += 256) {
        const unsigned ent = s_ent[w];
        const int bb = ent >> 10, m = ent & 1023;
        const float* gj = gall + (bb * NN + m) * 64 + 32;   // contiguous 128B gather
        const float* uu = s_u[bb];
        float ew = b2v;
        #pragma unroll
        for (int j = 0; j < 8; ++j) {
            const float4 gv = *reinterpret_cast<const float4*>(gj + 4 * j);
            ew = fmaf(fmaxf(uu[4 * j + 0] + gv.x, 0.f), s_w2[4 * j + 0], ew);
            ew = fmaf(fmaxf(uu[4 * j + 1] + gv.y, 0.f), s_w2[4 * j + 1], ew);
            ew = fmaf(fmaxf(uu[4 * j + 2] + gv.z, 0.f), s_w2[4 * j + 2], ew);
            ew = fmaf(fmaxf(uu[4 * j + 3] + gv.w, 0.f), s_w2[4 * j + 3], ew);
        }
        s_res[w] = 1.f / (1.f + __expf(-ew));
    }
    __syncthreads();

    #pragma unroll
    for (int b = 0; b < 2; ++b) {
        float4 r4;
        float* rp = &r4.x;
        #pragma unroll
        for (int cc = 0; cc < 4; ++cc) {
            const int slot = b * 4 + cc;
            rp[cc] = (eidx[slot] >= 0) ? ap[cc] * s_res[eidx[slot]] : 0.f;
        }
        *reinterpret_cast<float4*>(out + (size_t)(b * NN + n) * NN + m0) = r4;
    }
}

extern "C" void kernel_launch(void* const* d_in, const int* in_sizes, int n_in,
                              void* d_out, int out_size, void* d_ws, size_t ws_size,
                              hipStream_t stream)
{
    const float* nf  = (const float*)d_in[0];
    const float* adj = (const float*)d_in[1];
    const float* Wt  = (const float*)d_in[2];
    const float* bt  = (const float*)d_in[3];
    const float* W1  = (const float*)d_in[4];
    const float* b1  = (const float*)d_in[5];
    const float* W2  = (const float*)d_in[6];
    const float* b2  = (const float*)d_in[7];
    float* out  = (float*)d_out;
    float* gall = (float*)d_ws;   // 2048*64 floats

    hipLaunchKernelGGL(gall_kernel, dim3(256), dim3(256), 0, stream,
                       nf, Wt, bt, W1, b1, gall);
    hipLaunchKernelGGL(edge_kernel, dim3(NN), dim3(256), 0, stream,
                       adj, gall, W2, b2, out);
}